// Round 6
// baseline (52.012 us; speedup 1.0000x reference)
//
#include <hip/hip_runtime.h>
#include <hip/hip_bf16.h>

#define BB 8
#define NN 1024
#define HH 512
#define NEG 0.2f

typedef float f32x4 __attribute__((ext_vector_type(4)));
typedef short bf16x8 __attribute__((ext_vector_type(8)));
typedef unsigned int u32;

__device__ __forceinline__ unsigned short f2bf(float f) {
    union { float f; u32 u; } a; a.f = f;
    u32 u = a.u;
    u += 0x7fffu + ((u >> 16) & 1u);   // round-to-nearest-even
    return (unsigned short)(u >> 16);
}

// Kernel 1: per (batch, 32-row j-tile): s_src/s_dst dots + X^T bf16 [b][h][j]
// 512 thr, grid 256. Coalesced X reads (h = q*64 + l*4), 64B contiguous XT writes.
__global__ __launch_bounds__(512) void prep_kernel(
    const float* __restrict__ x, const float* __restrict__ wsrc,
    const float* __restrict__ wdst, float* __restrict__ ssrc,
    float* __restrict__ sdst, unsigned short* __restrict__ xt)
{
    __shared__ __align__(16) unsigned short lt[32][520];

    int bid = blockIdx.x;
    int b = bid & 7;
    int j0 = (bid >> 3) * 32;
    int t = threadIdx.x;
    int r = t >> 4;            // 0..31: row in tile
    int l = t & 15;

    const float* xrow = x + ((size_t)b * NN + j0 + r) * HH;
    float psrc = 0.f, pdst = 0.f;
    #pragma unroll
    for (int q = 0; q < 8; ++q) {
        int h = q * 64 + l * 4;
        f32x4 v = *(const f32x4*)(xrow + h);
        f32x4 a = *(const f32x4*)(wsrc + h);
        f32x4 d = *(const f32x4*)(wdst + h);
        psrc += v[0]*a[0] + v[1]*a[1] + v[2]*a[2] + v[3]*a[3];
        pdst += v[0]*d[0] + v[1]*d[1] + v[2]*d[2] + v[3]*d[3];
        u32 lo = (u32)f2bf(v[0]) | ((u32)f2bf(v[1]) << 16);
        u32 hi = (u32)f2bf(v[2]) | ((u32)f2bf(v[3]) << 16);
        *(u32*)&lt[r][h + 0] = lo;
        *(u32*)&lt[r][h + 2] = hi;
    }
    #pragma unroll
    for (int k = 1; k < 16; k <<= 1) {
        psrc += __shfl_xor(psrc, k);
        pdst += __shfl_xor(pdst, k);
    }
    if (l == 0) {
        ssrc[b * NN + j0 + r] = psrc;
        sdst[b * NN + j0 + r] = pdst;
    }
    __syncthreads();

    // thread t owns h = t; writes XT[b][h][j0..j0+31] = 64B contiguous
    unsigned short v[32];
    #pragma unroll
    for (int rr = 0; rr < 32; ++rr) v[rr] = lt[rr][t];
    unsigned short* dst = xt + ((size_t)b * HH + t) * NN + j0;
    #pragma unroll
    for (int q = 0; q < 4; ++q) {
        bf16x8 pk;
        #pragma unroll
        for (int e = 0; e < 8; ++e) pk[e] = (short)v[q*8 + e];
        *(bf16x8*)(dst + q * 8) = pk;
    }
}

// Kernel 2: FUSED softmax + PV. Block = (b, 32-row i-tile), grid 256 (1/CU),
// 512 thr / 8 waves; wave w owns h in [w*64, w*64+64).
// Sweep 1: all 1024 scores/row in regs (64/thread), adj coalesced, no score memory.
// Sweep 2: per 64-j tile: normalized bf16 P-tile -> swizzled LDS (dbuf, 1 barrier),
//          A-frags register-direct from L2-hot XT[b], 16 MFMA/wave/tile.
__global__ __launch_bounds__(512) void fgat_kernel(
    const float* __restrict__ ssrc, const float* __restrict__ sdst,
    const int* __restrict__ adj, const float* __restrict__ bptr,
    const unsigned short* __restrict__ xt, float* __restrict__ out)
{
    __shared__ __align__(16) float sd[NN];                  // 4KB: sdst[b][:]
    __shared__ float ss[32];
    __shared__ __align__(16) unsigned short Pt[2][32 * 64]; // 8KB: P-tile dbuf, swizzled

    int bid = blockIdx.x;
    int b = bid & 7;               // XCD-affine: XT[b] hot in this XCD's L2
    int i0 = (bid >> 3) * 32;
    int t = threadIdx.x;
    int lane = t & 63;
    int w = t >> 6;                // wave 0..7: h-chunk of 64
    int il = t >> 4;               // 0..31: i-row (16 threads per row)
    int jq = t & 15;               // j-quad within 64-j tile

    *(float2*)&sd[t * 2] = *(const float2*)&sdst[b * NN + t * 2];
    if (t < 32) ss[t] = ssrc[b * NN + i0 + t];
    __syncthreads();

    // ---- Sweep 1: scores in registers ----
    int ig = i0 + il;
    float si = ss[il] + bptr[0];
    const int* arow = adj + ((size_t)(b * NN + ig)) * NN;

    float sc[64];
    float m = -1e30f;
    #pragma unroll
    for (int T = 0; T < 16; ++T) {
        int j = T * 64 + jq * 4;
        int4 a4 = *(const int4*)(arow + j);
        f32x4 sv = *(const f32x4*)&sd[j];
        float s0 = si + sv[0]; s0 = s0 > 0.f ? s0 : NEG * s0;
        float s1 = si + sv[1]; s1 = s1 > 0.f ? s1 : NEG * s1;
        float s2 = si + sv[2]; s2 = s2 > 0.f ? s2 : NEG * s2;
        float s3 = si + sv[3]; s3 = s3 > 0.f ? s3 : NEG * s3;
        sc[T*4+0] = (a4.x != 0 || (j + 0) == ig) ? s0 : -1e30f;
        sc[T*4+1] = (a4.y != 0 || (j + 1) == ig) ? s1 : -1e30f;
        sc[T*4+2] = (a4.z != 0 || (j + 2) == ig) ? s2 : -1e30f;
        sc[T*4+3] = (a4.w != 0 || (j + 3) == ig) ? s3 : -1e30f;
        m = fmaxf(m, fmaxf(fmaxf(sc[T*4+0], sc[T*4+1]), fmaxf(sc[T*4+2], sc[T*4+3])));
    }
    #pragma unroll
    for (int k = 1; k < 16; k <<= 1) m = fmaxf(m, __shfl_xor(m, k));
    float sum = 0.f;
    #pragma unroll
    for (int k = 0; k < 64; ++k) { float e = __expf(sc[k] - m); sc[k] = e; sum += e; }
    #pragma unroll
    for (int k = 1; k < 16; k <<= 1) sum += __shfl_xor(sum, k);
    float inv = 1.f / sum;

    // ---- Sweep 2: per-tile P -> LDS, MFMA out^T ----
    int g = lane >> 4;
    int ln = lane & 15;
    const unsigned short* abase = xt + ((size_t)(b * HH + w * 64 + ln)) * NN + g * 8;

    // P-tile write byte (within one 4KB buf): layout [32][64] bf16, XOR-swizzled
    int wbyte = ((il * 64 + jq * 4) * 2) ^ ((il & 7) << 4);
    // B-frag read addrs into buf0; buf1 via +4096
    const char* pb[2][2];
    #pragma unroll
    for (int nb = 0; nb < 2; ++nb) {
        int row = nb * 16 + ln;
        #pragma unroll
        for (int kk = 0; kk < 2; ++kk)
            pb[nb][kk] = (const char*)&Pt[0][0] + (((row * 64 + kk * 32 + g * 8) * 2) ^ ((row & 7) << 4));
    }

    f32x4 acc[4][2];
    #pragma unroll
    for (int ma = 0; ma < 4; ++ma)
        #pragma unroll
        for (int nb = 0; nb < 2; ++nb)
            acc[ma][nb] = (f32x4){0.f, 0.f, 0.f, 0.f};

    #pragma unroll
    for (int T = 0; T < 16; ++T) {
        int buf = T & 1;
        // write normalized P-tile (bf16, swizzled)
        u32 lo = (u32)f2bf(sc[T*4+0] * inv) | ((u32)f2bf(sc[T*4+1] * inv) << 16);
        u32 hi = (u32)f2bf(sc[T*4+2] * inv) | ((u32)f2bf(sc[T*4+3] * inv) << 16);
        *(uint2*)((char*)&Pt[0][0] + buf * 4096 + wbyte) = make_uint2(lo, hi);

        // A-frags for this tile: register-direct from L2 (issued before barrier:
        // load latency overlaps the barrier wait)
        bf16x8 af[4][2];
        #pragma unroll
        for (int ma = 0; ma < 4; ++ma)
            #pragma unroll
            for (int kk = 0; kk < 2; ++kk)
                af[ma][kk] = *(const bf16x8*)(abase + (size_t)(ma * 16) * NN + T * 64 + kk * 32);

        __syncthreads();   // P-tile[buf] ready; prev tile's reads done (dbuf -> WAR-safe)

        bf16x8 bfr[2][2];
        #pragma unroll
        for (int nb = 0; nb < 2; ++nb)
            #pragma unroll
            for (int kk = 0; kk < 2; ++kk)
                bfr[nb][kk] = *(const bf16x8*)(pb[nb][kk] + buf * 4096);

        #pragma unroll
        for (int kk = 0; kk < 2; ++kk)
            #pragma unroll
            for (int ma = 0; ma < 4; ++ma)
                #pragma unroll
                for (int nb = 0; nb < 2; ++nb)
                    acc[ma][nb] = __builtin_amdgcn_mfma_f32_16x16x32_bf16(af[ma][kk], bfr[nb][kk], acc[ma][nb], 0, 0, 0);
    }

    // D: h = w*64 + ma*16 + g*4 + r, i = i0 + nb*16 + ln  (P pre-normalized)
    #pragma unroll
    for (int nb = 0; nb < 2; ++nb) {
        int i = i0 + nb * 16 + ln;
        #pragma unroll
        for (int ma = 0; ma < 4; ++ma) {
            float* dst = out + ((size_t)(b * NN + i)) * HH + w * 64 + ma * 16 + g * 4;
            *(f32x4*)dst = acc[ma][nb];
        }
    }
}

extern "C" void kernel_launch(void* const* d_in, const int* in_sizes, int n_in,
                              void* d_out, int out_size, void* d_ws, size_t ws_size,
                              hipStream_t stream) {
    const float* x    = (const float*)d_in[0];
    const int*   adj  = (const int*)d_in[1];
    const float* wsrc = (const float*)d_in[2];
    const float* wdst = (const float*)d_in[3];
    const float* bias = (const float*)d_in[4];
    float* out = (float*)d_out;

    // ws layout: ssrc(32KB) | sdst(32KB) | XT bf16 (8MB)
    float* ssrc = (float*)d_ws;
    float* sdst = ssrc + BB * NN;
    unsigned short* xt = (unsigned short*)(sdst + BB * NN);

    prep_kernel<<<dim3(BB * (NN / 32)), dim3(512), 0, stream>>>(x, wsrc, wdst, ssrc, sdst, xt);
    fgat_kernel<<<dim3(BB * (NN / 32)), dim3(512), 0, stream>>>(ssrc, sdst, adj, bias, xt, out);
}

// Round 7
// 37.682 us; speedup vs baseline: 1.3803x; 1.3803x over previous
//
#include <hip/hip_runtime.h>
#include <hip/hip_bf16.h>

#define BB 8
#define NN 1024
#define HH 512
#define NEG 0.2f

typedef float f32x4 __attribute__((ext_vector_type(4)));
typedef short bf16x8 __attribute__((ext_vector_type(8)));
typedef unsigned int u32;

__device__ __forceinline__ unsigned short f2bf(float f) {
    union { float f; u32 u; } a; a.f = f;
    u32 u = a.u;
    u += 0x7fffu + ((u >> 16) & 1u);   // round-to-nearest-even
    return (unsigned short)(u >> 16);
}

__device__ __forceinline__ void gload16(const void* g, void* l) {
    __builtin_amdgcn_global_load_lds(
        (const __attribute__((address_space(1))) unsigned int*)g,
        (__attribute__((address_space(3))) unsigned int*)l, 16, 0, 0);
}

// Kernel 1: per (batch, 16-row j-tile): s_src/s_dst dots + X^T bf16 [b][h][j]
// 512 thr, grid 512 (2 blocks/CU). Coalesced X reads, 32B contiguous XT writes.
__global__ __launch_bounds__(512) void prep_kernel(
    const float* __restrict__ x, const float* __restrict__ wsrc,
    const float* __restrict__ wdst, float* __restrict__ ssrc,
    float* __restrict__ sdst, unsigned short* __restrict__ xt)
{
    __shared__ __align__(16) unsigned short lt[16][528];

    int bid = blockIdx.x;
    int b = bid & 7;
    int j0 = (bid >> 3) * 16;
    int t = threadIdx.x;
    int r = t >> 5;            // 0..15: row in tile (32 threads per row)
    int l = t & 31;

    const float* xrow = x + ((size_t)(b * NN + j0 + r)) * HH;
    float psrc = 0.f, pdst = 0.f;
    #pragma unroll
    for (int q = 0; q < 4; ++q) {
        int h = q * 128 + l * 4;
        f32x4 v = *(const f32x4*)(xrow + h);
        f32x4 a = *(const f32x4*)(wsrc + h);
        f32x4 d = *(const f32x4*)(wdst + h);
        psrc += v[0]*a[0] + v[1]*a[1] + v[2]*a[2] + v[3]*a[3];
        pdst += v[0]*d[0] + v[1]*d[1] + v[2]*d[2] + v[3]*d[3];
        u32 lo = (u32)f2bf(v[0]) | ((u32)f2bf(v[1]) << 16);
        u32 hi = (u32)f2bf(v[2]) | ((u32)f2bf(v[3]) << 16);
        *(u32*)&lt[r][h + 0] = lo;
        *(u32*)&lt[r][h + 2] = hi;
    }
    // reduce across the 32 threads of this row (contiguous lanes, intra-wave)
    #pragma unroll
    for (int k = 1; k < 32; k <<= 1) {
        psrc += __shfl_xor(psrc, k);
        pdst += __shfl_xor(pdst, k);
    }
    if (l == 0) {
        ssrc[b * NN + j0 + r] = psrc;
        sdst[b * NN + j0 + r] = pdst;
    }
    __syncthreads();

    // thread t owns h = t; writes XT[b][h][j0..j0+15] = 32B contiguous
    unsigned short v[16];
    #pragma unroll
    for (int rr = 0; rr < 16; ++rr) v[rr] = lt[rr][t];
    unsigned short* dst = xt + ((size_t)(b * HH + t)) * NN + j0;
    #pragma unroll
    for (int q = 0; q < 2; ++q) {
        bf16x8 pk;
        #pragma unroll
        for (int e = 0; e < 8; ++e) pk[e] = (short)v[q*8 + e];
        *(bf16x8*)(dst + q * 8) = pk;
    }
}

// Kernel 2: softmax rows. 1 wave = 1 adjacency row. Writes NORMALIZED P (bf16).
__global__ __launch_bounds__(256) void softmax_kernel(
    const float* __restrict__ ssrc, const float* __restrict__ sdst,
    const int* __restrict__ adj, const float* __restrict__ bptr,
    unsigned short* __restrict__ P)
{
    __shared__ __align__(16) float sd[NN];

    int bid = blockIdx.x;
    int b = bid & 7;
    int r0 = (bid >> 3) * 4;
    int t = threadIdx.x;
    int lane = t & 63;
    int w = t >> 6;

    *(f32x4*)&sd[t * 4] = *(const f32x4*)&sdst[b * NN + t * 4];
    __syncthreads();

    int ig = r0 + w;
    float si = ssrc[b * NN + ig] + bptr[0];
    const int* arow = adj + ((size_t)b * NN + ig) * NN;

    float sc[16];
    float m = -1e30f;
    #pragma unroll
    for (int it = 0; it < 4; ++it) {
        int j = it * 256 + lane * 4;
        int4 a4 = *(const int4*)(arow + j);
        f32x4 sv = *(const f32x4*)&sd[j];
        float s0 = si + sv[0]; s0 = s0 > 0.f ? s0 : NEG * s0;
        float s1 = si + sv[1]; s1 = s1 > 0.f ? s1 : NEG * s1;
        float s2 = si + sv[2]; s2 = s2 > 0.f ? s2 : NEG * s2;
        float s3 = si + sv[3]; s3 = s3 > 0.f ? s3 : NEG * s3;
        sc[it*4+0] = (a4.x != 0 || (j + 0) == ig) ? s0 : -1e30f;
        sc[it*4+1] = (a4.y != 0 || (j + 1) == ig) ? s1 : -1e30f;
        sc[it*4+2] = (a4.z != 0 || (j + 2) == ig) ? s2 : -1e30f;
        sc[it*4+3] = (a4.w != 0 || (j + 3) == ig) ? s3 : -1e30f;
        m = fmaxf(m, fmaxf(fmaxf(sc[it*4+0], sc[it*4+1]), fmaxf(sc[it*4+2], sc[it*4+3])));
    }
    #pragma unroll
    for (int k = 1; k < 64; k <<= 1) m = fmaxf(m, __shfl_xor(m, k));
    float sum = 0.f;
    #pragma unroll
    for (int k = 0; k < 16; ++k) { float e = __expf(sc[k] - m); sc[k] = e; sum += e; }
    #pragma unroll
    for (int k = 1; k < 64; k <<= 1) sum += __shfl_xor(sum, k);
    float inv = 1.f / sum;

    unsigned short* prow = P + ((size_t)b * NN + ig) * NN;
    #pragma unroll
    for (int it = 0; it < 4; ++it) {
        int j = it * 256 + lane * 4;
        u32 lo = (u32)f2bf(sc[it*4+0] * inv) | ((u32)f2bf(sc[it*4+1] * inv) << 16);
        u32 hi = (u32)f2bf(sc[it*4+2] * inv) | ((u32)f2bf(sc[it*4+3] * inv) << 16);
        *(uint2*)(prow + j) = make_uint2(lo, hi);
    }
}

// Kernel 3: out^T GEMM, TRIPLE-buffered LDS staging + counted vmcnt (T4).
// Tile 128h x 64i, BK=64, 512 thr (8 waves = 4wm x 2wn, each 32h x 32i).
// Grid 8b x 4h x 16i = 512 (2 blocks/CU by 72KB LDS). One barrier per K-step;
// s_waitcnt vmcnt(3) leaves the next tile's 3 gloads in flight.
__global__ __launch_bounds__(512) void pv_kernel(
    const unsigned short* __restrict__ P, const unsigned short* __restrict__ xt,
    float* __restrict__ out)
{
    __shared__ __align__(16) unsigned short As[3 * 128 * 64]; // 48KB: buf stride 16384B
    __shared__ __align__(16) unsigned short Bs[3 * 64 * 64];  // 24KB: buf stride 8192B

    int bid = blockIdx.x;
    int b = bid & 7;              // XCD-affine
    int tt = bid >> 3;            // 0..63
    int h0 = (tt & 3) * 128;
    int i0 = (tt >> 2) * 64;
    int t = threadIdx.x;
    int lane = t & 63;
    int w = t >> 6;
    int wm = w & 3;               // h-subtile (32 rows)
    int wn = w >> 2;              // i-subtile (32 rows)
    int g = lane >> 4;
    int ln = lane & 15;

    // staging: thread t -> row0 = t>>3 (0..63), chunk c = t&7; linear LDS dest,
    // inverse-swizzled global source (both-sides rule #21)
    int row0 = t >> 3;
    int c = t & 7;
    int sj = (c ^ (row0 & 7)) * 8;
    const unsigned short* gA0 = xt + ((size_t)(b * HH + h0 + row0)) * NN + sj;
    const unsigned short* gA1 = gA0 + (size_t)64 * NN;
    const unsigned short* gB0 = P + ((size_t)(b * NN + i0 + row0)) * NN + sj;
    unsigned short* lA0 = As + t * 8;
    unsigned short* lA1 = As + 4096 + t * 8;
    unsigned short* lB0 = Bs + t * 8;

    // frag read addresses into buf0; buf k via +k*16384 (A) / +k*8192 (B) bytes
    const char* pa[2][2];
    #pragma unroll
    for (int ma = 0; ma < 2; ++ma) {
        int row = wm * 32 + ma * 16 + ln;
        #pragma unroll
        for (int kk = 0; kk < 2; ++kk)
            pa[ma][kk] = (const char*)As + ((row * 128 + kk * 64 + g * 16) ^ ((row & 7) << 4));
    }
    const char* pb[2][2];
    #pragma unroll
    for (int nb = 0; nb < 2; ++nb) {
        int row = wn * 32 + nb * 16 + ln;
        #pragma unroll
        for (int kk = 0; kk < 2; ++kk)
            pb[nb][kk] = (const char*)Bs + ((row * 128 + kk * 64 + g * 16) ^ ((row & 7) << 4));
    }

    f32x4 acc[2][2];
    #pragma unroll
    for (int ma = 0; ma < 2; ++ma)
        #pragma unroll
        for (int nb = 0; nb < 2; ++nb)
            acc[ma][nb] = (f32x4){0.f, 0.f, 0.f, 0.f};

    auto stage = [&](int p, int js) {   // 3 gload_lds per thread
        int joff = js * 64;
        gload16(gA0 + joff, lA0 + p * 8192);   // shorts: 8192 = 16KB
        gload16(gA1 + joff, lA1 + p * 8192);
        gload16(gB0 + joff, lB0 + p * 4096);   // shorts: 4096 = 8KB
    };
    auto compute = [&](int ofsA, int ofsB) {
        bf16x8 af[2][2], bfr[2][2];
        #pragma unroll
        for (int ma = 0; ma < 2; ++ma)
            #pragma unroll
            for (int kk = 0; kk < 2; ++kk)
                af[ma][kk] = *(const bf16x8*)(pa[ma][kk] + ofsA);
        #pragma unroll
        for (int nb = 0; nb < 2; ++nb)
            #pragma unroll
            for (int kk = 0; kk < 2; ++kk)
                bfr[nb][kk] = *(const bf16x8*)(pb[nb][kk] + ofsB);
        #pragma unroll
        for (int kk = 0; kk < 2; ++kk)
            #pragma unroll
            for (int ma = 0; ma < 2; ++ma)
                #pragma unroll
                for (int nb = 0; nb < 2; ++nb)
                    acc[ma][nb] = __builtin_amdgcn_mfma_f32_16x16x32_bf16(af[ma][kk], bfr[nb][kk], acc[ma][nb], 0, 0, 0);
    };

    stage(0, 0);
    stage(1, 1);
    int cur = 0, nx2 = 2;
    for (int js = 0; js < 16; ++js) {
        // wait ONLY the current tile's 3 loads (next tile's 3 stay in flight)
        if (js < 15) asm volatile("s_waitcnt vmcnt(3)" ::: "memory");
        else         asm volatile("s_waitcnt vmcnt(0)" ::: "memory");
        __builtin_amdgcn_sched_barrier(0);
        __builtin_amdgcn_s_barrier();       // all waves passed their vmcnt -> tile resident
        if (js + 2 < 16) stage(nx2, js + 2); // issue 2-ahead into the free buffer
        compute(cur * 16384, cur * 8192);
        cur = (cur == 2) ? 0 : cur + 1;
        nx2 = (nx2 == 2) ? 0 : nx2 + 1;
    }

    // D: h = h0+wm*32+ma*16+g*4+r, i = i0+wn*32+nb*16+ln
    #pragma unroll
    for (int nb = 0; nb < 2; ++nb) {
        int i = i0 + wn * 32 + nb * 16 + ln;
        #pragma unroll
        for (int ma = 0; ma < 2; ++ma) {
            float* dst = out + ((size_t)(b * NN + i)) * HH + h0 + wm * 32 + ma * 16 + g * 4;
            *(f32x4*)dst = acc[ma][nb];
        }
    }
}

extern "C" void kernel_launch(void* const* d_in, const int* in_sizes, int n_in,
                              void* d_out, int out_size, void* d_ws, size_t ws_size,
                              hipStream_t stream) {
    const float* x    = (const float*)d_in[0];
    const int*   adj  = (const int*)d_in[1];
    const float* wsrc = (const float*)d_in[2];
    const float* wdst = (const float*)d_in[3];
    const float* bias = (const float*)d_in[4];
    float* out = (float*)d_out;

    // ws layout: ssrc(32KB) | sdst(32KB) | XT bf16 (8MB) | P bf16 (16MB)
    float* ssrc = (float*)d_ws;
    float* sdst = ssrc + BB * NN;
    unsigned short* xt = (unsigned short*)(sdst + BB * NN);
    unsigned short* P  = xt + (size_t)BB * HH * NN;

    prep_kernel<<<dim3(BB * (NN / 16)), dim3(512), 0, stream>>>(x, wsrc, wdst, ssrc, sdst, xt);
    softmax_kernel<<<dim3(BB * NN / 4), dim3(256), 0, stream>>>(ssrc, sdst, adj, bias, P);
    pv_kernel<<<dim3(BB * 4 * 16), dim3(512), 0, stream>>>(P, xt, out);
}